// Round 1
// baseline (501.106 us; speedup 1.0000x reference)
//
#include <hip/hip_runtime.h>

#define NB    8
#define CIN   768
#define LSP   4096
#define DD    96
#define COUT_ 768

typedef __attribute__((ext_vector_type(4))) float f32x4;
typedef __attribute__((ext_vector_type(8))) __bf16 bf16x8;
typedef __attribute__((ext_vector_type(8))) unsigned short us8;

static __device__ __forceinline__ unsigned short f2bf(float f){
  union{float f; unsigned u;} v; v.f=f;
  unsigned r = v.u + 0x7FFFu + ((v.u>>16)&1u);
  return (unsigned short)(r>>16);
}
static __device__ __forceinline__ float bf2f(unsigned short s){
  union{unsigned u; float f;} v; v.u=((unsigned)s)<<16; return v.f;
}
static __device__ __forceinline__ f32x4 mfma16(us8 a, us8 b, f32x4 c){
  union UA{us8 u; bf16x8 b;};
  UA A; A.u=a; UA B; B.u=b;
  return __builtin_amdgcn_mfma_f32_16x16x32_bf16(A.b, B.b, c, 0, 0, 0);
}

// ---------------- K0: weight prep (split Wq/Wk into bf16 hi+lo, cvt Wv/Wlast)
__global__ __launch_bounds__(256) void prep_w(
    const float* __restrict__ Wq, const float* __restrict__ Wk,
    const float* __restrict__ Wv, const float* __restrict__ Wl,
    unsigned short* __restrict__ wqh, unsigned short* __restrict__ wql,
    unsigned short* __restrict__ wkh, unsigned short* __restrict__ wkl,
    unsigned short* __restrict__ wvb, unsigned short* __restrict__ wlb){
  int i = blockIdx.x*256 + threadIdx.x;
  if (i < 96*768){
    float q = Wq[i]; unsigned short h = f2bf(q); wqh[i]=h; wql[i]=f2bf(q - bf2f(h));
    float k = Wk[i]; h = f2bf(k); wkh[i]=h; wkl[i]=f2bf(k - bf2f(h));
    wvb[i] = f2bf(Wv[i]);
    wlb[i] = f2bf(Wl[i]);
  }
}

// ---------------- K1: fused QKV projection
// q,k: D[m=l][n=o] = sum_c X^T[l][c] * W[o][c]  (split-bf16, 3 MFMA terms)
// v:   D[m=o][n=l] = sum_c Wv[o][c] * X[c][l]   (plain bf16, reuses x_hi frag)
__global__ __launch_bounds__(256) void proj_qkv(const float* __restrict__ x,
    const unsigned short* __restrict__ wqh, const unsigned short* __restrict__ wql,
    const unsigned short* __restrict__ wkh, const unsigned short* __restrict__ wkl,
    const unsigned short* __restrict__ wvb,
    unsigned short* __restrict__ qh, unsigned short* __restrict__ ql,
    unsigned short* __restrict__ kh, unsigned short* __restrict__ kl,
    unsigned short* __restrict__ vt){
  __shared__ __attribute__((aligned(16))) unsigned short xt_h[64*40];  // [l][c] c-chunk 32 (+8 pad)
  __shared__ __attribute__((aligned(16))) unsigned short xt_l[64*40];
  __shared__ __attribute__((aligned(16))) unsigned short swq_h[96*40]; // [o][c]
  __shared__ __attribute__((aligned(16))) unsigned short swq_l[96*40];
  __shared__ __attribute__((aligned(16))) unsigned short swk_h[96*40];
  __shared__ __attribute__((aligned(16))) unsigned short swk_l[96*40];
  __shared__ __attribute__((aligned(16))) unsigned short swv [96*40];

  const int t = threadIdx.x;
  const int b = blockIdx.y;
  const int l0 = blockIdx.x*64;
  const int w = t>>6, lane = t&63, m16 = lane&15, quad = lane>>4;

  f32x4 zz = {0.f,0.f,0.f,0.f};
  f32x4 accq[6], acck[6], accv[6];
  #pragma unroll
  for (int i=0;i<6;i++){ accq[i]=zz; acck[i]=zz; accv[i]=zz; }

  const float* xb = x + (size_t)b*CIN*LSP;
  const int ci = t>>3, lj = (t&7)*8;

  #pragma unroll 1
  for (int cc=0; cc<24; ++cc){
    const int c0 = cc*32;
    __syncthreads();
    // stage x^T tile [64 l][32 c], split into hi/lo
    {
      const float* src = xb + (size_t)(c0+ci)*LSP + l0 + lj;
      f32x4 v0 = *(const f32x4*)src;
      f32x4 v1 = *(const f32x4*)(src+4);
      #pragma unroll
      for (int j=0;j<4;j++){
        float f = v0[j]; unsigned short h=f2bf(f);
        xt_h[(lj+j)*40+ci]=h; xt_l[(lj+j)*40+ci]=f2bf(f-bf2f(h));
      }
      #pragma unroll
      for (int j=0;j<4;j++){
        float f = v1[j]; unsigned short h=f2bf(f);
        xt_h[(lj+4+j)*40+ci]=h; xt_l[(lj+4+j)*40+ci]=f2bf(f-bf2f(h));
      }
    }
    // stage weight tiles [96 o][32 c] (5 arrays)
    for (int u=t; u<384; u+=256){
      const int o = u>>2, sg = (u&3)*8;
      const int g = o*CIN + c0 + sg;
      const int d = o*40 + sg;
      *(us8*)&swq_h[d] = *(const us8*)&wqh[g];
      *(us8*)&swq_l[d] = *(const us8*)&wql[g];
      *(us8*)&swk_h[d] = *(const us8*)&wkh[g];
      *(us8*)&swk_l[d] = *(const us8*)&wkl[g];
      *(us8*)&swv [d]  = *(const us8*)&wvb[g];
    }
    __syncthreads();

    const int lrow = w*16 + m16;
    us8 axh = *(const us8*)&xt_h[lrow*40 + quad*8];
    us8 axl = *(const us8*)&xt_l[lrow*40 + quad*8];
    #pragma unroll
    for (int nt=0; nt<6; ++nt){
      const int wr = (nt*16 + m16)*40 + quad*8;
      us8 bh = *(const us8*)&swq_h[wr];
      us8 bl = *(const us8*)&swq_l[wr];
      accq[nt] = mfma16(axh, bh, accq[nt]);
      accq[nt] = mfma16(axh, bl, accq[nt]);
      accq[nt] = mfma16(axl, bh, accq[nt]);
      bh = *(const us8*)&swk_h[wr];
      bl = *(const us8*)&swk_l[wr];
      acck[nt] = mfma16(axh, bh, acck[nt]);
      acck[nt] = mfma16(axh, bl, acck[nt]);
      acck[nt] = mfma16(axl, bh, acck[nt]);
      us8 av = *(const us8*)&swv[wr];
      accv[nt] = mfma16(av, axh, accv[nt]);   // v: A=Wv, B=x (same frag as axh)
    }
  }
  // epilogue: q,k -> hi/lo bf16 [B,L,96]; v -> bf16 [B,96,L]
  #pragma unroll
  for (int nt=0; nt<6; ++nt){
    #pragma unroll
    for (int r=0; r<4; ++r){
      const int l = l0 + w*16 + quad*4 + r;
      const int o = nt*16 + m16;
      size_t qi = ((size_t)b*LSP + l)*DD + o;
      float fq = accq[nt][r];
      unsigned short h = f2bf(fq);
      qh[qi]=h; ql[qi]=f2bf(fq - bf2f(h));
      float fk = acck[nt][r];
      h = f2bf(fk);
      kh[qi]=h; kl[qi]=f2bf(fk - bf2f(h));
      const int vo = nt*16 + quad*4 + r;
      const int vl = l0 + w*16 + m16;
      vt[((size_t)b*DD + vo)*LSP + vl] = f2bf(accv[nt][r]);
    }
  }
}

// ---------------- K2: flash attention, TQ=64 (4 waves x 16 q-rows), TK=64
__global__ __launch_bounds__(256) void flash_attn(
    const unsigned short* __restrict__ qh, const unsigned short* __restrict__ ql,
    const unsigned short* __restrict__ kh, const unsigned short* __restrict__ kl,
    const unsigned short* __restrict__ vt, unsigned short* __restrict__ outb){
  __shared__ __attribute__((aligned(16))) unsigned short sk_h[64*104]; // [kj][d] +8 pad
  __shared__ __attribute__((aligned(16))) unsigned short sk_l[64*104];
  __shared__ __attribute__((aligned(16))) unsigned short sv  [96*72];  // [d][kj] +8 pad
  __shared__ __attribute__((aligned(16))) unsigned short sp  [4*16*72]; // per-wave P

  const int t = threadIdx.x;
  const int b = blockIdx.y;
  const int l0 = blockIdx.x*64;
  const int w = t>>6, lane = t&63, m16 = lane&15, quad = lane>>4;

  // Q fragments straight from global (A-layout is 16B-contiguous in memory)
  us8 aqh[3], aql[3];
  {
    const int qrow = l0 + w*16 + m16;
    size_t qo = ((size_t)b*LSP + qrow)*DD;
    #pragma unroll
    for (int ks=0;ks<3;ks++){
      aqh[ks] = *(const us8*)&qh[qo + ks*32 + quad*8];
      aql[ks] = *(const us8*)&ql[qo + ks*32 + quad*8];
    }
  }
  f32x4 zz = {0.f,0.f,0.f,0.f};
  f32x4 accO[6];
  #pragma unroll
  for (int i=0;i<6;i++) accO[i]=zz;
  float m_run[4], l_run[4];
  #pragma unroll
  for (int r=0;r<4;r++){ m_run[r]=-3.0e38f; l_run[r]=0.f; }

  const int srow = t>>2, sseg = (t&3)*24;

  #pragma unroll 1
  for (int kt=0; kt<64; ++kt){
    const int lk = kt*64;
    __syncthreads();
    {
      size_t kg = ((size_t)b*LSP + lk + srow)*DD + sseg;
      #pragma unroll
      for (int j=0;j<3;j++){
        *(us8*)&sk_h[srow*104 + sseg + j*8] = *(const us8*)&kh[kg + j*8];
        *(us8*)&sk_l[srow*104 + sseg + j*8] = *(const us8*)&kl[kg + j*8];
      }
      #pragma unroll
      for (int i=0;i<3;i++){
        const int u = t + i*256;
        const int vr = u>>3, vs = (u&7)*8;
        *(us8*)&sv[vr*72 + vs] = *(const us8*)&vt[((size_t)b*DD + vr)*LSP + lk + vs];
      }
    }
    __syncthreads();

    // scores: S = Q.K^T in split-bf16 (3 terms)
    f32x4 s[4];
    #pragma unroll
    for (int nt=0; nt<4; ++nt){
      s[nt]=zz;
      const int kr = (nt*16 + m16)*104 + quad*8;
      #pragma unroll
      for (int ks=0; ks<3; ++ks){
        us8 bh = *(const us8*)&sk_h[kr + ks*32];
        us8 bl = *(const us8*)&sk_l[kr + ks*32];
        s[nt] = mfma16(aqh[ks], bh, s[nt]);
        s[nt] = mfma16(aqh[ks], bl, s[nt]);
        s[nt] = mfma16(aql[ks], bh, s[nt]);
      }
    }
    // online softmax (rows live in 16-lane quad groups)
    float mnew[4], alpha[4];
    #pragma unroll
    for (int r=0;r<4;r++){
      float tm = fmaxf(fmaxf(s[0][r], s[1][r]), fmaxf(s[2][r], s[3][r]));
      tm = fmaxf(tm, __shfl_xor(tm, 1));
      tm = fmaxf(tm, __shfl_xor(tm, 2));
      tm = fmaxf(tm, __shfl_xor(tm, 4));
      tm = fmaxf(tm, __shfl_xor(tm, 8));
      mnew[r] = fmaxf(m_run[r], tm);
      alpha[r] = __expf(m_run[r] - mnew[r]);
      m_run[r] = mnew[r];
    }
    float p[4][4];
    #pragma unroll
    for (int nt=0;nt<4;nt++){
      #pragma unroll
      for (int r=0;r<4;r++) p[nt][r] = __expf(s[nt][r] - mnew[r]);
    }
    #pragma unroll
    for (int r=0;r<4;r++){
      float su = (p[0][r]+p[1][r])+(p[2][r]+p[3][r]);
      su += __shfl_xor(su, 1);
      su += __shfl_xor(su, 2);
      su += __shfl_xor(su, 4);
      su += __shfl_xor(su, 8);
      l_run[r] = l_run[r]*alpha[r] + su;
    }
    #pragma unroll
    for (int dt=0;dt<6;dt++){
      #pragma unroll
      for (int r=0;r<4;r++) accO[dt][r] *= alpha[r];
    }
    // restage P (C-layout) -> A-layout via per-wave LDS (same-wave DS ordering)
    const int pb = w*16*72;
    #pragma unroll
    for (int nt=0;nt<4;nt++){
      #pragma unroll
      for (int r=0;r<4;r++)
        sp[pb + (quad*4+r)*72 + nt*16 + m16] = f2bf(p[nt][r]);
    }
    // O += P.V
    #pragma unroll
    for (int k2=0;k2<2;k2++){
      us8 ap = *(const us8*)&sp[pb + m16*72 + k2*32 + quad*8];
      #pragma unroll
      for (int dt=0;dt<6;dt++){
        us8 bv = *(const us8*)&sv[(dt*16+m16)*72 + k2*32 + quad*8];
        accO[dt] = mfma16(ap, bv, accO[dt]);
      }
    }
  }
  #pragma unroll
  for (int dt=0;dt<6;dt++){
    #pragma unroll
    for (int r=0;r<4;r++){
      const int l = l0 + w*16 + quad*4 + r;
      const int d = dt*16 + m16;
      outb[((size_t)b*LSP + l)*DD + d] = f2bf(accO[dt][r] / l_run[r]);
    }
  }
}

// ---------------- K3: y = gamma * (out @ Wlast^T) + x
__global__ __launch_bounds__(256) void lastproj(
    const unsigned short* __restrict__ outb, const unsigned short* __restrict__ wlb,
    const float* __restrict__ x, const float* __restrict__ gamma, float* __restrict__ y){
  __shared__ __attribute__((aligned(16))) unsigned short so [64*104]; // [l][d]
  __shared__ __attribute__((aligned(16))) unsigned short swl[64*104]; // [o][d]
  const int t = threadIdx.x;
  const int b  = blockIdx.z;
  const int o0 = blockIdx.y*64;
  const int l0 = blockIdx.x*64;
  const int srow = t>>2, sseg = (t&3)*24;
  {
    size_t og = ((size_t)b*LSP + l0 + srow)*DD + sseg;
    size_t wg = (size_t)(o0 + srow)*DD + sseg;
    #pragma unroll
    for (int j=0;j<3;j++){
      *(us8*)&so [srow*104 + sseg + j*8] = *(const us8*)&outb[og + j*8];
      *(us8*)&swl[srow*104 + sseg + j*8] = *(const us8*)&wlb[wg + j*8];
    }
  }
  __syncthreads();
  const int w = t>>6, lane = t&63, m16 = lane&15, quad = lane>>4;
  us8 aw[3];
  #pragma unroll
  for (int ks=0;ks<3;ks++) aw[ks] = *(const us8*)&swl[(w*16+m16)*104 + ks*32 + quad*8];
  f32x4 zz = {0.f,0.f,0.f,0.f};
  f32x4 acc[4];
  #pragma unroll
  for (int i=0;i<4;i++) acc[i]=zz;
  #pragma unroll
  for (int nt=0;nt<4;nt++){
    const int orow = (nt*16+m16)*104;
    #pragma unroll
    for (int ks=0;ks<3;ks++){
      us8 bo = *(const us8*)&so[orow + ks*32 + quad*8];
      acc[nt] = mfma16(aw[ks], bo, acc[nt]);
    }
  }
  const float g = gamma[0];
  #pragma unroll
  for (int nt=0;nt<4;nt++){
    #pragma unroll
    for (int r=0;r<4;r++){
      const int o = o0 + w*16 + quad*4 + r;
      const int l = l0 + nt*16 + m16;
      size_t idx = ((size_t)b*COUT_ + o)*LSP + l;
      y[idx] = g*acc[nt][r] + x[idx];
    }
  }
}

extern "C" void kernel_launch(void* const* d_in, const int* in_sizes, int n_in,
                              void* d_out, int out_size, void* d_ws, size_t ws_size,
                              hipStream_t stream){
  (void)in_sizes; (void)n_in; (void)out_size; (void)ws_size;
  const float* x  = (const float*)d_in[0];
  const float* Wq = (const float*)d_in[1];
  const float* Wk = (const float*)d_in[2];
  const float* Wv = (const float*)d_in[3];
  const float* Wl = (const float*)d_in[4];
  const float* gm = (const float*)d_in[5];
  float* y = (float*)d_out;

  char* p = (char*)d_ws;
  const size_t big = (size_t)NB*LSP*DD*2;   // 6,291,456 B each
  unsigned short* qh  = (unsigned short*)p; p += big;
  unsigned short* ql_ = (unsigned short*)p; p += big;
  unsigned short* kh  = (unsigned short*)p; p += big;
  unsigned short* kl  = (unsigned short*)p; p += big;
  unsigned short* vt  = (unsigned short*)p; p += big;
  unsigned short* ob  = (unsigned short*)p; p += big;
  const size_t wsz = (size_t)96*768*2;      // 147,456 B each
  unsigned short* wqh=(unsigned short*)p; p+=wsz;
  unsigned short* wql=(unsigned short*)p; p+=wsz;
  unsigned short* wkh=(unsigned short*)p; p+=wsz;
  unsigned short* wkl=(unsigned short*)p; p+=wsz;
  unsigned short* wvb=(unsigned short*)p; p+=wsz;
  unsigned short* wlb=(unsigned short*)p; p+=wsz;

  prep_w   <<<dim3(288),      dim3(256), 0, stream>>>(Wq,Wk,Wv,Wl,wqh,wql,wkh,wkl,wvb,wlb);
  proj_qkv <<<dim3(64,8),     dim3(256), 0, stream>>>(x,wqh,wql,wkh,wkl,wvb,qh,ql_,kh,kl,vt);
  flash_attn<<<dim3(64,8),    dim3(256), 0, stream>>>(qh,ql_,kh,kl,vt,ob);
  lastproj <<<dim3(64,12,8),  dim3(256), 0, stream>>>(ob,wlb,x,gm,y);
}

// Round 3
// 343.532 us; speedup vs baseline: 1.4587x; 1.4587x over previous
//
#include <hip/hip_runtime.h>

#define NB    8
#define CIN   768
#define LSP   4096
#define DD    96
#define COUT_ 768

typedef __attribute__((ext_vector_type(4))) float f32x4;
typedef __attribute__((ext_vector_type(8))) __bf16 bf16x8;
typedef __attribute__((ext_vector_type(8))) unsigned short us8;
typedef __attribute__((ext_vector_type(4))) unsigned short us4;

static __device__ __forceinline__ unsigned short f2bf(float f){
  union{float f; unsigned u;} v; v.f=f;
  unsigned r = v.u + 0x7FFFu + ((v.u>>16)&1u);
  return (unsigned short)(r>>16);
}
static __device__ __forceinline__ float bf2f(unsigned short s){
  union{unsigned u; float f;} v; v.u=((unsigned)s)<<16; return v.f;
}
static __device__ __forceinline__ unsigned fbits(float f){
  union{float f; unsigned u;} v; v.f=f; return v.u;
}
// pack two floats -> (bf16(hi)<<16)|bf16(lo)  (truncation)
static __device__ __forceinline__ unsigned pack2(float lo, float hi){
  return __builtin_amdgcn_perm(fbits(hi), fbits(lo), 0x07060302u);
}
static __device__ __forceinline__ f32x4 mfma16(us8 a, us8 b, f32x4 c){
  union UA{us8 u; bf16x8 b;};
  UA A; A.u=a; UA B; B.u=b;
  return __builtin_amdgcn_mfma_f32_16x16x32_bf16(A.b, B.b, c, 0, 0, 0);
}

// ---------------- K0: weight prep (split Wq/Wk into bf16 hi+lo, cvt Wv/Wlast)
__global__ __launch_bounds__(256) void prep_w(
    const float* __restrict__ Wq, const float* __restrict__ Wk,
    const float* __restrict__ Wv, const float* __restrict__ Wl,
    unsigned short* __restrict__ wqh, unsigned short* __restrict__ wql,
    unsigned short* __restrict__ wkh, unsigned short* __restrict__ wkl,
    unsigned short* __restrict__ wvb, unsigned short* __restrict__ wlb){
  int i = blockIdx.x*256 + threadIdx.x;
  if (i < 96*768){
    float q = Wq[i]; unsigned short h = f2bf(q); wqh[i]=h; wql[i]=f2bf(q - bf2f(h));
    float k = Wk[i]; h = f2bf(k); wkh[i]=h; wkl[i]=f2bf(k - bf2f(h));
    wvb[i] = f2bf(Wv[i]);
    wlb[i] = f2bf(Wl[i]);
  }
}

// ---------------- K1: fused QKV projection (unchanged, verified round 1)
__global__ __launch_bounds__(256) void proj_qkv(const float* __restrict__ x,
    const unsigned short* __restrict__ wqh, const unsigned short* __restrict__ wql,
    const unsigned short* __restrict__ wkh, const unsigned short* __restrict__ wkl,
    const unsigned short* __restrict__ wvb,
    unsigned short* __restrict__ qh, unsigned short* __restrict__ ql,
    unsigned short* __restrict__ kh, unsigned short* __restrict__ kl,
    unsigned short* __restrict__ vt){
  __shared__ __attribute__((aligned(16))) unsigned short xt_h[64*40];
  __shared__ __attribute__((aligned(16))) unsigned short xt_l[64*40];
  __shared__ __attribute__((aligned(16))) unsigned short swq_h[96*40];
  __shared__ __attribute__((aligned(16))) unsigned short swq_l[96*40];
  __shared__ __attribute__((aligned(16))) unsigned short swk_h[96*40];
  __shared__ __attribute__((aligned(16))) unsigned short swk_l[96*40];
  __shared__ __attribute__((aligned(16))) unsigned short swv [96*40];

  const int t = threadIdx.x;
  const int b = blockIdx.y;
  const int l0 = blockIdx.x*64;
  const int w = t>>6, lane = t&63, m16 = lane&15, quad = lane>>4;

  f32x4 zz = {0.f,0.f,0.f,0.f};
  f32x4 accq[6], acck[6], accv[6];
  #pragma unroll
  for (int i=0;i<6;i++){ accq[i]=zz; acck[i]=zz; accv[i]=zz; }

  const float* xb = x + (size_t)b*CIN*LSP;
  const int ci = t>>3, lj = (t&7)*8;

  #pragma unroll 1
  for (int cc=0; cc<24; ++cc){
    const int c0 = cc*32;
    __syncthreads();
    {
      const float* src = xb + (size_t)(c0+ci)*LSP + l0 + lj;
      f32x4 v0 = *(const f32x4*)src;
      f32x4 v1 = *(const f32x4*)(src+4);
      #pragma unroll
      for (int j=0;j<4;j++){
        float f = v0[j]; unsigned short h=f2bf(f);
        xt_h[(lj+j)*40+ci]=h; xt_l[(lj+j)*40+ci]=f2bf(f-bf2f(h));
      }
      #pragma unroll
      for (int j=0;j<4;j++){
        float f = v1[j]; unsigned short h=f2bf(f);
        xt_h[(lj+4+j)*40+ci]=h; xt_l[(lj+4+j)*40+ci]=f2bf(f-bf2f(h));
      }
    }
    for (int u=t; u<384; u+=256){
      const int o = u>>2, sg = (u&3)*8;
      const int g = o*CIN + c0 + sg;
      const int d = o*40 + sg;
      *(us8*)&swq_h[d] = *(const us8*)&wqh[g];
      *(us8*)&swq_l[d] = *(const us8*)&wql[g];
      *(us8*)&swk_h[d] = *(const us8*)&wkh[g];
      *(us8*)&swk_l[d] = *(const us8*)&wkl[g];
      *(us8*)&swv [d]  = *(const us8*)&wvb[g];
    }
    __syncthreads();

    const int lrow = w*16 + m16;
    us8 axh = *(const us8*)&xt_h[lrow*40 + quad*8];
    us8 axl = *(const us8*)&xt_l[lrow*40 + quad*8];
    #pragma unroll
    for (int nt=0; nt<6; ++nt){
      const int wr = (nt*16 + m16)*40 + quad*8;
      us8 bh = *(const us8*)&swq_h[wr];
      us8 bl = *(const us8*)&swq_l[wr];
      accq[nt] = mfma16(axh, bh, accq[nt]);
      accq[nt] = mfma16(axh, bl, accq[nt]);
      accq[nt] = mfma16(axl, bh, accq[nt]);
      bh = *(const us8*)&swk_h[wr];
      bl = *(const us8*)&swk_l[wr];
      acck[nt] = mfma16(axh, bh, acck[nt]);
      acck[nt] = mfma16(axh, bl, acck[nt]);
      acck[nt] = mfma16(axl, bh, acck[nt]);
      us8 av = *(const us8*)&swv[wr];
      accv[nt] = mfma16(av, axh, accv[nt]);
    }
  }
  #pragma unroll
  for (int nt=0; nt<6; ++nt){
    #pragma unroll
    for (int r=0; r<4; ++r){
      const int l = l0 + w*16 + quad*4 + r;
      const int o = nt*16 + m16;
      size_t qi = ((size_t)b*LSP + l)*DD + o;
      float fq = accq[nt][r];
      unsigned short h = f2bf(fq);
      qh[qi]=h; ql[qi]=f2bf(fq - bf2f(h));
      float fk = acck[nt][r];
      h = f2bf(fk);
      kh[qi]=h; kl[qi]=f2bf(fk - bf2f(h));
      const int vo = nt*16 + quad*4 + r;
      const int vl = l0 + w*16 + m16;
      vt[((size_t)b*DD + vo)*LSP + vl] = f2bf(accv[nt][r]);
    }
  }
}

// ---------------- K2: flash attention v3
// S^T: D[m=k][n=q], A=K (plain [64][96] LDS, conflict-free), B=Q (regs).
// 32 q per wave (2 groups of 16) -> every K/V LDS read feeds 2 MFMAs.
// PV uses permuted k-order kappa(k2,quad,j)=32k2+16(j>>2)+4quad+(j&3):
//   B-frag = lane's own P values (no cross-lane transpose at all);
//   V staged into LDS pre-permuted to match.
__global__ __launch_bounds__(256, 2) void flash_attn3(
    const unsigned short* __restrict__ qh, const unsigned short* __restrict__ ql,
    const unsigned short* __restrict__ kh, const unsigned short* __restrict__ kl,
    const unsigned short* __restrict__ vt,
    unsigned short* __restrict__ U, float* __restrict__ Ms, float* __restrict__ Ls){
  __shared__ __attribute__((aligned(16))) unsigned short sk_h[64*96];
  __shared__ __attribute__((aligned(16))) unsigned short sk_l[64*96];
  __shared__ __attribute__((aligned(16))) unsigned short sv  [96*72];

  const int bid = blockIdx.x;
  const int b   = bid & 7;            // batch pinned to XCD
  const int qt  = (bid >> 3) & 31;
  const int sp  = bid >> 8;           // split-K index
  const int l0  = qt*128;
  const int t = threadIdx.x;
  const int w = t>>6, lane = t&63, m16 = lane&15, quad = lane>>4;

  // Q fragments (B-operand), 2 groups of 16 q per wave
  us8 bqh[2][3], bql[2][3];
  #pragma unroll
  for (int g=0; g<2; ++g){
    const int lq = l0 + w*32 + g*16 + m16;
    size_t qo = ((size_t)b*LSP + lq)*DD;
    #pragma unroll
    for (int ks=0;ks<3;ks++){
      bqh[g][ks] = *(const us8*)&qh[qo + ks*32 + quad*8];
      bql[g][ks] = *(const us8*)&ql[qo + ks*32 + quad*8];
    }
  }

  // staging thread maps
  const int krow = t>>2, kc = (t&3);
  const int kg_off = krow*DD + kc*24;
  const int ksw    = krow*96 + kc*24;
  const int vd = t>>3, vc = t&7;
  const int vg_off = vd*LSP + vc*8;
  const int sigb = 32*((vc>>2)&1) + 16*(vc&1) + 4*((vc>>1)&1);
  const int vw = vd*72 + sigb;

  f32x4 zz = {0.f,0.f,0.f,0.f};
  f32x4 accO[2][6];
  #pragma unroll
  for (int g=0;g<2;g++)
    #pragma unroll
    for (int i=0;i<6;i++) accO[g][i]=zz;
  float mr[2] = {-3.0e38f, -3.0e38f}, lr[2] = {0.f, 0.f};

  const unsigned short* kh_it = kh + ((size_t)b*LSP + sp*2048)*DD;
  const unsigned short* kl_it = kl + ((size_t)b*LSP + sp*2048)*DD;
  const unsigned short* vt_it = vt + (size_t)b*DD*LSP + sp*2048;

  // preload tile 0
  us8 rh[3], rl[3], rv[3];
  #pragma unroll
  for (int j=0;j<3;j++){
    rh[j] = *(const us8*)(kh_it + kg_off + j*8);
    rl[j] = *(const us8*)(kl_it + kg_off + j*8);
    rv[j] = *(const us8*)(vt_it + vg_off + j*32*LSP);
  }

  #pragma unroll 1
  for (int kt=0; kt<32; ++kt){
    __syncthreads();
    #pragma unroll
    for (int j=0;j<3;j++){
      *(us8*)&sk_h[ksw + j*8] = rh[j];
      *(us8*)&sk_l[ksw + j*8] = rl[j];
      union { us8 v; us4 h[2]; } u; u.v = rv[j];
      *(us4*)&sv[vw + j*32*72]     = u.h[0];
      *(us4*)&sv[vw + j*32*72 + 8] = u.h[1];
    }
    kh_it += 64*DD; kl_it += 64*DD; vt_it += 64;
    if (kt < 31){
      #pragma unroll
      for (int j=0;j<3;j++){
        rh[j] = *(const us8*)(kh_it + kg_off + j*8);
        rl[j] = *(const us8*)(kl_it + kg_off + j*8);
        rv[j] = *(const us8*)(vt_it + vg_off + j*32*LSP);
      }
    }
    __syncthreads();

    // S^T = K . Q^T, split-bf16 3 terms; K reads shared across both q-groups
    f32x4 s[2][4];
    #pragma unroll
    for (int nt=0; nt<4; ++nt){
      s[0][nt]=zz; s[1][nt]=zz;
      const int kr = (nt*16+m16)*96 + quad*8;
      #pragma unroll
      for (int ks=0; ks<3; ++ks){
        us8 ah = *(const us8*)&sk_h[kr + ks*32];
        us8 al = *(const us8*)&sk_l[kr + ks*32];
        #pragma unroll
        for (int g=0; g<2; ++g){
          s[g][nt] = mfma16(ah, bqh[g][ks], s[g][nt]);
          s[g][nt] = mfma16(ah, bql[g][ks], s[g][nt]);
          s[g][nt] = mfma16(al, bqh[g][ks], s[g][nt]);
        }
      }
    }

    // online softmax + pack P (per group); lane owns one q-row per group
    us8 bp[2][2];
    #pragma unroll
    for (int g=0; g<2; ++g){
      float tm = s[g][0][0];
      #pragma unroll
      for (int nt=0;nt<4;nt++){
        #pragma unroll
        for (int r=0;r<4;r++) tm = fmaxf(tm, s[g][nt][r]);
      }
      tm = fmaxf(tm, __shfl_xor(tm, 16));
      tm = fmaxf(tm, __shfl_xor(tm, 32));
      float mn = fmaxf(mr[g], tm);
      float al = __expf(mr[g] - mn);
      mr[g] = mn;
      float p[4][4];
      float su = 0.f;
      #pragma unroll
      for (int nt=0;nt<4;nt++){
        #pragma unroll
        for (int r=0;r<4;r++){ p[nt][r] = __expf(s[g][nt][r] - mn); su += p[nt][r]; }
      }
      su += __shfl_xor(su, 16);
      su += __shfl_xor(su, 32);
      lr[g] = lr[g]*al + su;
      #pragma unroll
      for (int dt=0;dt<6;dt++){
        #pragma unroll
        for (int r=0;r<4;r++) accO[g][dt][r] *= al;
      }
      // B-frag for PV mfma k2: shorts {p[2k2][0..3], p[2k2+1][0..3]}
      #pragma unroll
      for (int k2=0;k2<2;k2++){
        union {unsigned u[4]; us8 v;} pb;
        pb.u[0] = pack2(p[2*k2][0],   p[2*k2][1]);
        pb.u[1] = pack2(p[2*k2][2],   p[2*k2][3]);
        pb.u[2] = pack2(p[2*k2+1][0], p[2*k2+1][1]);
        pb.u[3] = pack2(p[2*k2+1][2], p[2*k2+1][3]);
        bp[g][k2] = pb.v;
      }
    }

    // O^T += V~ . P~ : A = permuted-V (LDS), B = own-lane P; V reads shared
    #pragma unroll
    for (int k2=0;k2<2;k2++){
      #pragma unroll
      for (int dt=0;dt<6;dt++){
        us8 av = *(const us8*)&sv[(dt*16+m16)*72 + k2*32 + quad*8];
        accO[0][dt] = mfma16(av, bp[0][k2], accO[0][dt]);
        accO[1][dt] = mfma16(av, bp[1][k2], accO[1][dt]);
      }
    }
  }

  // store partials: U (unnormalized O, bf16), m, l
  #pragma unroll
  for (int g=0; g<2; ++g){
    const int q = l0 + w*32 + g*16 + m16;
    size_t ub = (((size_t)sp*NB + b)*LSP + q)*DD;
    #pragma unroll
    for (int dt=0;dt<6;dt++){
      #pragma unroll
      for (int r=0;r<4;r++)
        U[ub + dt*16 + quad*4 + r] = f2bf(accO[g][dt][r]);
    }
    if (quad == 0){
      size_t mi = ((size_t)sp*NB + b)*LSP + q;
      Ms[mi] = mr[g];
      Ls[mi] = lr[g];
    }
  }
}

// ---------------- K2b: merge the 2 split-K partials
__global__ __launch_bounds__(256) void merge2(
    const unsigned short* __restrict__ U, const float* __restrict__ Ms,
    const float* __restrict__ Ls, unsigned short* __restrict__ ob){
  int idx = blockIdx.x*256 + threadIdx.x;     // 8*4096*12
  int row = idx / 12, ch = idx % 12;
  float m0 = Ms[row],          m1 = Ms[NB*LSP + row];
  float l0 = Ls[row],          l1 = Ls[NB*LSP + row];
  float M  = fmaxf(m0, m1);
  float w0 = __expf(m0 - M), w1 = __expf(m1 - M);
  float inv = 1.0f/(w0*l0 + w1*l1);
  w0 *= inv; w1 *= inv;
  us8 u0 = *(const us8*)&U[(size_t)row*DD + ch*8];
  us8 u1 = *(const us8*)&U[(size_t)NB*LSP*DD + (size_t)row*DD + ch*8];
  us8 o;
  #pragma unroll
  for (int j=0;j<8;j++) o[j] = f2bf(w0*bf2f(u0[j]) + w1*bf2f(u1[j]));
  *(us8*)&ob[(size_t)row*DD + ch*8] = o;
}

// ---------------- K3: y = gamma * (out @ Wlast^T) + x
__global__ __launch_bounds__(256) void lastproj(
    const unsigned short* __restrict__ outb, const unsigned short* __restrict__ wlb,
    const float* __restrict__ x, const float* __restrict__ gamma, float* __restrict__ y){
  __shared__ __attribute__((aligned(16))) unsigned short so [64*104];
  __shared__ __attribute__((aligned(16))) unsigned short swl[64*104];
  const int t = threadIdx.x;
  const int bid = blockIdx.x;
  const int b  = bid & 7;
  const int r2 = bid >> 3;            // 0..767
  const int o0 = (r2 % 12)*64;
  const int l0 = (r2 / 12)*64;
  const int srow = t>>2, sseg = (t&3)*24;
  {
    size_t og = ((size_t)b*LSP + l0 + srow)*DD + sseg;
    size_t wg = (size_t)(o0 + srow)*DD + sseg;
    #pragma unroll
    for (int j=0;j<3;j++){
      *(us8*)&so [srow*104 + sseg + j*8] = *(const us8*)&outb[og + j*8];
      *(us8*)&swl[srow*104 + sseg + j*8] = *(const us8*)&wlb[wg + j*8];
    }
  }
  __syncthreads();
  const int w = t>>6, lane = t&63, m16 = lane&15, quad = lane>>4;
  us8 aw[3];
  #pragma unroll
  for (int ks=0;ks<3;ks++) aw[ks] = *(const us8*)&swl[(w*16+m16)*104 + ks*32 + quad*8];
  f32x4 zz = {0.f,0.f,0.f,0.f};
  f32x4 acc[4];
  #pragma unroll
  for (int i=0;i<4;i++) acc[i]=zz;
  #pragma unroll
  for (int nt=0;nt<4;nt++){
    const int orow = (nt*16+m16)*104;
    #pragma unroll
    for (int ks=0;ks<3;ks++){
      us8 bo = *(const us8*)&so[orow + ks*32 + quad*8];
      acc[nt] = mfma16(aw[ks], bo, acc[nt]);
    }
  }
  const float g = gamma[0];
  #pragma unroll
  for (int nt=0;nt<4;nt++){
    #pragma unroll
    for (int r=0;r<4;r++){
      const int o = o0 + w*16 + quad*4 + r;
      const int l = l0 + nt*16 + m16;
      size_t idx = ((size_t)b*COUT_ + o)*LSP + l;
      y[idx] = g*acc[nt][r] + x[idx];
    }
  }
}

extern "C" void kernel_launch(void* const* d_in, const int* in_sizes, int n_in,
                              void* d_out, int out_size, void* d_ws, size_t ws_size,
                              hipStream_t stream){
  (void)in_sizes; (void)n_in; (void)out_size; (void)ws_size;
  const float* x  = (const float*)d_in[0];
  const float* Wq = (const float*)d_in[1];
  const float* Wk = (const float*)d_in[2];
  const float* Wv = (const float*)d_in[3];
  const float* Wl = (const float*)d_in[4];
  const float* gm = (const float*)d_in[5];
  float* y = (float*)d_out;

  char* p = (char*)d_ws;
  const size_t big = (size_t)NB*LSP*DD*2;   // 6,291,456 B each
  unsigned short* qh  = (unsigned short*)p; p += big;
  unsigned short* ql_ = (unsigned short*)p; p += big;
  unsigned short* kh  = (unsigned short*)p; p += big;
  unsigned short* kl  = (unsigned short*)p; p += big;
  unsigned short* vt  = (unsigned short*)p; p += big;
  unsigned short* ob  = (unsigned short*)p; p += big;
  unsigned short* Ubuf = (unsigned short*)p; p += 2*big;          // split-K partials
  float* Ms = (float*)p; p += (size_t)2*NB*LSP*sizeof(float);
  float* Ls = (float*)p; p += (size_t)2*NB*LSP*sizeof(float);
  const size_t wsz = (size_t)96*768*2;
  unsigned short* wqh=(unsigned short*)p; p+=wsz;
  unsigned short* wql=(unsigned short*)p; p+=wsz;
  unsigned short* wkh=(unsigned short*)p; p+=wsz;
  unsigned short* wkl=(unsigned short*)p; p+=wsz;
  unsigned short* wvb=(unsigned short*)p; p+=wsz;
  unsigned short* wlb=(unsigned short*)p; p+=wsz;

  prep_w    <<<dim3(288),  dim3(256), 0, stream>>>(Wq,Wk,Wv,Wl,wqh,wql,wkh,wkl,wvb,wlb);
  proj_qkv  <<<dim3(64,8), dim3(256), 0, stream>>>(x,wqh,wql,wkh,wkl,wvb,qh,ql_,kh,kl,vt);
  flash_attn3<<<dim3(512), dim3(256), 0, stream>>>(qh,ql_,kh,kl,vt,Ubuf,Ms,Ls);
  merge2    <<<dim3(1536), dim3(256), 0, stream>>>(Ubuf,Ms,Ls,ob);
  lastproj  <<<dim3(6144), dim3(256), 0, stream>>>(ob,wlb,x,gm,y);
}